// Round 1
// baseline (171.950 us; speedup 1.0000x reference)
//
#include <hip/hip_runtime.h>

// CrossAttention on MI355X (gfx950), bf16 MFMA pipeline.
// B=8 SQ=4096 SKV=77 DE=512 DC=768 H=8 DH=64.

typedef __attribute__((ext_vector_type(8))) __bf16 bf16x8;
typedef __attribute__((ext_vector_type(4))) float f32x4;

#define DEVI static __device__ __forceinline__

DEVI unsigned short f2bf(float f) {
  unsigned int u = __float_as_uint(f);
  u += 0x7FFFu + ((u >> 16) & 1u);   // round-to-nearest-even
  return (unsigned short)(u >> 16);
}

// ---------------------------------------------------------------------------
// Weight transpose + fp32->bf16: in [K][N] f32 -> out [N][K] bf16
// ---------------------------------------------------------------------------
__global__ __launch_bounds__(256) void wtrans_kernel(const float* __restrict__ in,
                                                     unsigned short* __restrict__ out,
                                                     int K, int N) {
  __shared__ float tile[32][33];
  int n0 = blockIdx.x * 32, k0 = blockIdx.y * 32;
  int tx = threadIdx.x, ty = threadIdx.y;  // 32 x 8
#pragma unroll
  for (int j = 0; j < 4; ++j)
    tile[ty * 4 + j][tx] = in[(size_t)(k0 + ty * 4 + j) * N + n0 + tx];
  __syncthreads();
#pragma unroll
  for (int j = 0; j < 4; ++j)
    out[(size_t)(n0 + ty * 4 + j) * K + k0 + tx] = f2bf(tile[tx][ty * 4 + j]);
}

// ---------------------------------------------------------------------------
// K/V projection: ctxflat [616][768] f32 @ wT [512][768] bf16 (+bias) ->
//   sel=0: Kp [B][H][80][64] bf16 (rows >=77 stay zero via memset)
//   sel=1: Vt [B][H][64][96] bf16 (cols >=77 stay zero via memset)
// grid = 2 * 10 * 8 = 160 blocks, 256 threads (4 waves), 64x64 tile, K=768.
// ---------------------------------------------------------------------------
__global__ __launch_bounds__(256) void kv_proj_kernel(const float* __restrict__ ctx,
                                                      const unsigned short* __restrict__ wkT,
                                                      const unsigned short* __restrict__ wvT,
                                                      const float* __restrict__ bk,
                                                      const float* __restrict__ bv,
                                                      unsigned short* __restrict__ Kp,
                                                      unsigned short* __restrict__ Vt) {
  __shared__ __align__(16) unsigned short As[64][40];
  __shared__ __align__(16) unsigned short Bs[64][40];
  int bid = blockIdx.x;
  int sel = bid / 80;
  int rem = bid % 80;
  int mt = rem / 8, nt = rem % 8;
  const unsigned short* wT = sel ? wvT : wkT;
  const float* bias = sel ? bv : bk;
  int tid = threadIdx.x;
  int l = tid & 63, w = tid >> 6;
  int lr = l & 15, lg = l >> 4;

  f32x4 acc[4] = {};
  for (int k0 = 0; k0 < 768; k0 += 32) {
    // stage A: 64 rows x 32 k fp32 -> bf16
#pragma unroll
    for (int it = 0; it < 2; ++it) {
      int idx4 = it * 256 + tid;     // 0..511 float4 slots
      int r = idx4 >> 3, q4 = idx4 & 7;
      int m = mt * 64 + r;
      float4 v = {0.f, 0.f, 0.f, 0.f};
      if (m < 616) v = *(const float4*)(ctx + (size_t)m * 768 + k0 + q4 * 4);
      ushort4 o;
      o.x = f2bf(v.x); o.y = f2bf(v.y); o.z = f2bf(v.z); o.w = f2bf(v.w);
      *(ushort4*)&As[r][q4 * 4] = o;
    }
    // stage B: 64 cols x 32 k bf16 (already transposed)
    {
      int c = tid >> 2, q8 = tid & 3;
      *(uint4*)&Bs[c][q8 * 8] =
          *(const uint4*)(wT + (size_t)(nt * 64 + c) * 768 + k0 + q8 * 8);
    }
    __syncthreads();
    bf16x8 a = *(const bf16x8*)&As[w * 16 + lr][lg * 8];
#pragma unroll
    for (int n = 0; n < 4; ++n) {
      bf16x8 bb = *(const bf16x8*)&Bs[n * 16 + lr][lg * 8];
      acc[n] = __builtin_amdgcn_mfma_f32_16x16x32_bf16(a, bb, acc[n], 0, 0, 0);
    }
    __syncthreads();
  }
#pragma unroll
  for (int n = 0; n < 4; ++n) {
#pragma unroll
    for (int reg = 0; reg < 4; ++reg) {
      int m = mt * 64 + w * 16 + lg * 4 + reg;
      if (m < 616) {
        int bI = m / 77, s = m % 77;
        int col = nt * 64 + n * 16 + lr;
        int h = col >> 6, d = col & 63;
        float v = acc[n][reg] + bias[col];
        if (sel == 0)
          Kp[(((size_t)(bI * 8 + h)) * 80 + s) * 64 + d] = f2bf(v);
        else
          Vt[(((size_t)(bI * 8 + h)) * 64 + d) * 96 + s] = f2bf(v);
      }
    }
  }
}

// ---------------------------------------------------------------------------
// GEMM: [32768][512] @ BT[512][512](bf16, row=out col) + bias.
// A_BF16: A is bf16 (else fp32, converted on stage). OUT_F32: fp32 out else bf16.
// 128x128 tile, 256 threads (4 waves 2x2), K=512 in 32-steps.
// ---------------------------------------------------------------------------
template <int A_BF16, int OUT_F32>
__global__ __launch_bounds__(256) void gemm512_kernel(const void* __restrict__ Ain,
                                                      const unsigned short* __restrict__ BT,
                                                      const float* __restrict__ bias,
                                                      void* __restrict__ Out) {
  __shared__ __align__(16) unsigned short As[128][40];
  __shared__ __align__(16) unsigned short Bs[128][40];
  int bid = blockIdx.x;
  size_t mbase = (size_t)(bid >> 2) * 128;
  int nbase = (bid & 3) * 128;
  int tid = threadIdx.x;
  int l = tid & 63, w = tid >> 6;
  int lr = l & 15, lg = l >> 4;
  int wr = (w >> 1) * 64, wc = (w & 1) * 64;

  f32x4 acc[4][4] = {};
  for (int k0 = 0; k0 < 512; k0 += 32) {
    if constexpr (!A_BF16) {
      const float* A = (const float*)Ain;
#pragma unroll
      for (int it = 0; it < 4; ++it) {
        int idx4 = it * 256 + tid;   // 1024 float4 slots
        int r = idx4 >> 3, q4 = idx4 & 7;
        float4 v = *(const float4*)(A + (mbase + r) * 512 + k0 + q4 * 4);
        ushort4 o;
        o.x = f2bf(v.x); o.y = f2bf(v.y); o.z = f2bf(v.z); o.w = f2bf(v.w);
        *(ushort4*)&As[r][q4 * 4] = o;
      }
    } else {
      const unsigned short* A = (const unsigned short*)Ain;
#pragma unroll
      for (int it = 0; it < 2; ++it) {
        int idx8 = it * 256 + tid;   // 512 vec8 slots
        int r = idx8 >> 2, q8 = idx8 & 3;
        *(uint4*)&As[r][q8 * 8] =
            *(const uint4*)(A + (mbase + r) * 512 + k0 + q8 * 8);
      }
    }
#pragma unroll
    for (int it = 0; it < 2; ++it) {
      int idx8 = it * 256 + tid;
      int c = idx8 >> 2, q8 = idx8 & 3;
      *(uint4*)&Bs[c][q8 * 8] =
          *(const uint4*)(BT + (size_t)(nbase + c) * 512 + k0 + q8 * 8);
    }
    __syncthreads();
    bf16x8 af[4], bv8[4];
#pragma unroll
    for (int m = 0; m < 4; ++m) af[m] = *(const bf16x8*)&As[wr + m * 16 + lr][lg * 8];
#pragma unroll
    for (int n = 0; n < 4; ++n) bv8[n] = *(const bf16x8*)&Bs[wc + n * 16 + lr][lg * 8];
#pragma unroll
    for (int m = 0; m < 4; ++m)
#pragma unroll
      for (int n = 0; n < 4; ++n)
        acc[m][n] = __builtin_amdgcn_mfma_f32_16x16x32_bf16(af[m], bv8[n], acc[m][n], 0, 0, 0);
    __syncthreads();
  }
  // epilogue: D row = lg*4+reg, col = lr (verified m89 layout)
#pragma unroll
  for (int m = 0; m < 4; ++m) {
#pragma unroll
    for (int n = 0; n < 4; ++n) {
#pragma unroll
      for (int reg = 0; reg < 4; ++reg) {
        size_t row = mbase + wr + m * 16 + lg * 4 + reg;
        int col = nbase + wc + n * 16 + lr;
        float v = acc[m][n][reg] + bias[col];
        if constexpr (OUT_F32)
          ((float*)Out)[row * 512 + col] = v;
        else
          ((unsigned short*)Out)[row * 512 + col] = f2bf(v);
      }
    }
  }
}

// ---------------------------------------------------------------------------
// Fused attention: per block (b, h, 64 q-rows); 4 waves x 16 rows.
// QK^T via MFMA (K tiles of 16 over padded 80), fp32 softmax (mask col>=77),
// P -> LDS bf16 (96-pad), PV via MFMA, written in-place over Q.
// ---------------------------------------------------------------------------
__global__ __launch_bounds__(256) void attn_kernel(unsigned short* __restrict__ Q,
                                                   const unsigned short* __restrict__ Kp,
                                                   const unsigned short* __restrict__ Vt) {
  __shared__ __align__(16) unsigned short P[4][16][104];
  int tid = threadIdx.x;
  int l = tid & 63, w = tid >> 6;
  int lr = l & 15, lg = l >> 4;
  int bid = blockIdx.x;
  int qb = bid & 63;
  int h = (bid >> 6) & 7;
  int b = bid >> 9;

  // zero the P pad columns [80..96) once (only cols <96 are ever read)
  for (int z = l; z < 16 * 16; z += 64) {
    P[w][z >> 4][80 + (z & 15)] = 0;
  }

  size_t qrow0 = (size_t)b * 4096 + qb * 64 + w * 16;
  const size_t qoff = (qrow0 + lr) * 512 + h * 64 + lg * 8;
  bf16x8 aq0 = *(const bf16x8*)(Q + qoff);
  bf16x8 aq1 = *(const bf16x8*)(Q + qoff + 32);

  const unsigned short* Kph = Kp + (size_t)(b * 8 + h) * 80 * 64;
  f32x4 s[5] = {};
#pragma unroll
  for (int t = 0; t < 5; ++t) {
    const unsigned short* kr = Kph + (t * 16 + lr) * 64 + lg * 8;
    bf16x8 b0 = *(const bf16x8*)kr;
    bf16x8 b1 = *(const bf16x8*)(kr + 32);
    s[t] = __builtin_amdgcn_mfma_f32_16x16x32_bf16(aq0, b0, s[t], 0, 0, 0);
    s[t] = __builtin_amdgcn_mfma_f32_16x16x32_bf16(aq1, b1, s[t], 0, 0, 0);
  }
  if (lr >= 13) {  // cols 64+lr >= 77 are padding
    s[4][0] = -1e30f; s[4][1] = -1e30f; s[4][2] = -1e30f; s[4][3] = -1e30f;
  }

  // softmax over 77 cols; row r = lg*4+reg, cols spread over lr lanes x 5 tiles
  float mx[4], sm[4];
#pragma unroll
  for (int r = 0; r < 4; ++r)
    mx[r] = fmaxf(fmaxf(fmaxf(s[0][r], s[1][r]), fmaxf(s[2][r], s[3][r])), s[4][r]);
#pragma unroll
  for (int d = 1; d < 16; d <<= 1)
#pragma unroll
    for (int r = 0; r < 4; ++r) mx[r] = fmaxf(mx[r], __shfl_xor(mx[r], d, 64));

  const float C = 0.125f * 1.44269504088896f;  // scale * log2(e)
  float p[5][4];
#pragma unroll
  for (int t = 0; t < 5; ++t)
#pragma unroll
    for (int r = 0; r < 4; ++r) p[t][r] = exp2f((s[t][r] - mx[r]) * C);
#pragma unroll
  for (int r = 0; r < 4; ++r)
    sm[r] = p[0][r] + p[1][r] + p[2][r] + p[3][r] + p[4][r];
#pragma unroll
  for (int d = 1; d < 16; d <<= 1)
#pragma unroll
    for (int r = 0; r < 4; ++r) sm[r] += __shfl_xor(sm[r], d, 64);
#pragma unroll
  for (int r = 0; r < 4; ++r) sm[r] = 1.0f / sm[r];
#pragma unroll
  for (int t = 0; t < 5; ++t)
#pragma unroll
    for (int r = 0; r < 4; ++r)
      P[w][lg * 4 + r][t * 16 + lr] = f2bf(p[t][r] * sm[r]);

  __syncthreads();

  // PV: A = P [16 x 96], B = V^T-stored [96 x 64]
  const unsigned short* Vth = Vt + (size_t)(b * 8 + h) * 64 * 96;
  bf16x8 ap[3];
#pragma unroll
  for (int c = 0; c < 3; ++c) ap[c] = *(const bf16x8*)&P[w][lr][c * 32 + lg * 8];
#pragma unroll
  for (int ct = 0; ct < 4; ++ct) {
    f32x4 o = {};
#pragma unroll
    for (int c = 0; c < 3; ++c) {
      bf16x8 bv8 = *(const bf16x8*)(Vth + (size_t)(ct * 16 + lr) * 96 + c * 32 + lg * 8);
      o = __builtin_amdgcn_mfma_f32_16x16x32_bf16(ap[c], bv8, o, 0, 0, 0);
    }
#pragma unroll
    for (int reg = 0; reg < 4; ++reg) {
      Q[(qrow0 + lg * 4 + reg) * 512 + h * 64 + ct * 16 + lr] = f2bf(o[reg]);
    }
  }
}

// ---------------------------------------------------------------------------
// Workspace layout (bytes)
// ---------------------------------------------------------------------------
static const size_t OFF_Q   = 0;                         // 8*4096*512*2 = 33554432
static const size_t OFF_KP  = 33554432;                  // 8*8*80*64*2  = 655360
static const size_t OFF_VT  = OFF_KP + 655360;           // 8*8*64*96*2  = 786432
static const size_t OFF_WQT = OFF_VT + 786432;           // 512*512*2    = 524288
static const size_t OFF_WKT = OFF_WQT + 524288;          // 512*768*2    = 786432
static const size_t OFF_WVT = OFF_WKT + 786432;          // 512*768*2    = 786432
static const size_t OFF_WOT = OFF_WVT + 786432;          // 512*512*2    = 524288
static const size_t WS_NEEDED = OFF_WOT + 524288;        // 37617664

extern "C" void kernel_launch(void* const* d_in, const int* in_sizes, int n_in,
                              void* d_out, int out_size, void* d_ws, size_t ws_size,
                              hipStream_t stream) {
  (void)in_sizes; (void)n_in; (void)out_size;
  if (ws_size < WS_NEEDED) return;  // cannot run without scratch

  const float* latent  = (const float*)d_in[0];
  const float* context = (const float*)d_in[1];
  const float* wq = (const float*)d_in[2];
  const float* bq = (const float*)d_in[3];
  const float* wk = (const float*)d_in[4];
  const float* bk = (const float*)d_in[5];
  const float* wv = (const float*)d_in[6];
  const float* bv = (const float*)d_in[7];
  const float* wo = (const float*)d_in[8];
  const float* bo = (const float*)d_in[9];
  float* out = (float*)d_out;

  char* ws = (char*)d_ws;
  unsigned short* wsQ = (unsigned short*)(ws + OFF_Q);
  unsigned short* Kp  = (unsigned short*)(ws + OFF_KP);
  unsigned short* Vt  = (unsigned short*)(ws + OFF_VT);
  unsigned short* wqT = (unsigned short*)(ws + OFF_WQT);
  unsigned short* wkT = (unsigned short*)(ws + OFF_WKT);
  unsigned short* wvT = (unsigned short*)(ws + OFF_WVT);
  unsigned short* woT = (unsigned short*)(ws + OFF_WOT);

  dim3 tb(32, 8);
  wtrans_kernel<<<dim3(16, 16), tb, 0, stream>>>(wq, wqT, 512, 512);
  wtrans_kernel<<<dim3(16, 24), tb, 0, stream>>>(wk, wkT, 768, 512);
  wtrans_kernel<<<dim3(16, 24), tb, 0, stream>>>(wv, wvT, 768, 512);
  wtrans_kernel<<<dim3(16, 16), tb, 0, stream>>>(wo, woT, 512, 512);

  hipMemsetAsync(ws + OFF_KP, 0, 655360 + 786432, stream);

  kv_proj_kernel<<<160, 256, 0, stream>>>(context, wkT, wvT, bk, bv, Kp, Vt);
  gemm512_kernel<0, 0><<<1024, 256, 0, stream>>>((const void*)latent, wqT, bq, (void*)wsQ);
  attn_kernel<<<4096, 256, 0, stream>>>(wsQ, Kp, Vt);
  gemm512_kernel<1, 1><<<1024, 256, 0, stream>>>((const void*)wsQ, woT, bo, (void*)out);
}

// Round 2
// 167.044 us; speedup vs baseline: 1.0294x; 1.0294x over previous
//
#include <hip/hip_runtime.h>

// CrossAttention on MI355X (gfx950), bf16 MFMA pipeline, round 2.
// B=8 SQ=4096 SKV=77 DE=512 DC=768 H=8 DH=64.
// R2 change: m97-style GEMM (global_load_lds width-16, linear LDS) for the two
// 32768x512x512 GEMMs + upfront latent fp32->bf16 pass staged in d_out.

typedef __attribute__((ext_vector_type(8))) __bf16 bf16x8;
typedef __attribute__((ext_vector_type(4))) float f32x4;

#define DEVI static __device__ __forceinline__

typedef __attribute__((address_space(3))) void lds_void_t;
typedef const __attribute__((address_space(1))) void gbl_void_t;
#define GLDS16(gsrc, ldst) \
  __builtin_amdgcn_global_load_lds((gbl_void_t*)(gsrc), (lds_void_t*)(ldst), 16, 0, 0)

DEVI unsigned short f2bf(float f) {
  unsigned int u = __float_as_uint(f);
  u += 0x7FFFu + ((u >> 16) & 1u);   // round-to-nearest-even
  return (unsigned short)(u >> 16);
}

DEVI unsigned int pack2bf(float a, float b) {
  return (unsigned int)f2bf(a) | ((unsigned int)f2bf(b) << 16);
}

// ---------------------------------------------------------------------------
// latent fp32 -> bf16, 8 elems/thread (32B read, 16B write per lane)
// ---------------------------------------------------------------------------
__global__ __launch_bounds__(256) void cvt_bf16_kernel(const float* __restrict__ in,
                                                       unsigned int* __restrict__ out4) {
  int i = blockIdx.x * 256 + threadIdx.x;   // one per 8 elements
  const float4* in4 = (const float4*)in;
  float4 a = in4[2 * i];
  float4 b = in4[2 * i + 1];
  uint4 o;
  o.x = pack2bf(a.x, a.y);
  o.y = pack2bf(a.z, a.w);
  o.z = pack2bf(b.x, b.y);
  o.w = pack2bf(b.z, b.w);
  *(uint4*)(out4 + 4 * (size_t)i) = o;
}

// ---------------------------------------------------------------------------
// Weight transpose + fp32->bf16: in [K][N] f32 -> out [N][K] bf16
// ---------------------------------------------------------------------------
__global__ __launch_bounds__(256) void wtrans_kernel(const float* __restrict__ in,
                                                     unsigned short* __restrict__ out,
                                                     int K, int N) {
  __shared__ float tile[32][33];
  int n0 = blockIdx.x * 32, k0 = blockIdx.y * 32;
  int tx = threadIdx.x, ty = threadIdx.y;  // 32 x 8
#pragma unroll
  for (int j = 0; j < 4; ++j)
    tile[ty * 4 + j][tx] = in[(size_t)(k0 + ty * 4 + j) * N + n0 + tx];
  __syncthreads();
#pragma unroll
  for (int j = 0; j < 4; ++j)
    out[(size_t)(n0 + ty * 4 + j) * K + k0 + tx] = f2bf(tile[tx][ty * 4 + j]);
}

// ---------------------------------------------------------------------------
// K/V projection (unchanged from passing R1)
// ---------------------------------------------------------------------------
__global__ __launch_bounds__(256) void kv_proj_kernel(const float* __restrict__ ctx,
                                                      const unsigned short* __restrict__ wkT,
                                                      const unsigned short* __restrict__ wvT,
                                                      const float* __restrict__ bk,
                                                      const float* __restrict__ bv,
                                                      unsigned short* __restrict__ Kp,
                                                      unsigned short* __restrict__ Vt) {
  __shared__ __align__(16) unsigned short As[64][40];
  __shared__ __align__(16) unsigned short Bs[64][40];
  int bid = blockIdx.x;
  int sel = bid / 80;
  int rem = bid % 80;
  int mt = rem / 8, nt = rem % 8;
  const unsigned short* wT = sel ? wvT : wkT;
  const float* bias = sel ? bv : bk;
  int tid = threadIdx.x;
  int l = tid & 63, w = tid >> 6;
  int lr = l & 15, lg = l >> 4;

  f32x4 acc[4] = {};
  for (int k0 = 0; k0 < 768; k0 += 32) {
#pragma unroll
    for (int it = 0; it < 2; ++it) {
      int idx4 = it * 256 + tid;
      int r = idx4 >> 3, q4 = idx4 & 7;
      int m = mt * 64 + r;
      float4 v = {0.f, 0.f, 0.f, 0.f};
      if (m < 616) v = *(const float4*)(ctx + (size_t)m * 768 + k0 + q4 * 4);
      ushort4 o;
      o.x = f2bf(v.x); o.y = f2bf(v.y); o.z = f2bf(v.z); o.w = f2bf(v.w);
      *(ushort4*)&As[r][q4 * 4] = o;
    }
    {
      int c = tid >> 2, q8 = tid & 3;
      *(uint4*)&Bs[c][q8 * 8] =
          *(const uint4*)(wT + (size_t)(nt * 64 + c) * 768 + k0 + q8 * 8);
    }
    __syncthreads();
    bf16x8 a = *(const bf16x8*)&As[w * 16 + lr][lg * 8];
#pragma unroll
    for (int n = 0; n < 4; ++n) {
      bf16x8 bb = *(const bf16x8*)&Bs[n * 16 + lr][lg * 8];
      acc[n] = __builtin_amdgcn_mfma_f32_16x16x32_bf16(a, bb, acc[n], 0, 0, 0);
    }
    __syncthreads();
  }
#pragma unroll
  for (int n = 0; n < 4; ++n) {
#pragma unroll
    for (int reg = 0; reg < 4; ++reg) {
      int m = mt * 64 + w * 16 + lg * 4 + reg;
      if (m < 616) {
        int bI = m / 77, s = m % 77;
        int col = nt * 64 + n * 16 + lr;
        int h = col >> 6, d = col & 63;
        float v = acc[n][reg] + bias[col];
        if (sel == 0)
          Kp[(((size_t)(bI * 8 + h)) * 80 + s) * 64 + d] = f2bf(v);
        else
          Vt[(((size_t)(bI * 8 + h)) * 64 + d) * 96 + s] = f2bf(v);
      }
    }
  }
}

// ---------------------------------------------------------------------------
// m97-style GEMM: A [32768][512] bf16 @ BT [512][512] bf16 (+bias f32).
// 128x128 tile, 4 waves (2x2), BK=32, global_load_lds width-16, linear LDS.
// OUT_F32: fp32 out else bf16.
// ---------------------------------------------------------------------------
template <int OUT_F32>
__global__ __launch_bounds__(256) void gemm512_glds_kernel(
    const unsigned short* __restrict__ A, const unsigned short* __restrict__ BT,
    const float* __restrict__ bias, void* __restrict__ Out) {
  __shared__ __align__(16) unsigned short As[128 * 32];  // row*32 + k, 64B/row
  __shared__ __align__(16) unsigned short Bs[128 * 32];
  int bid = blockIdx.x;
  size_t mbase = (size_t)(bid >> 2) * 128;
  int nbase = (bid & 3) * 128;
  int tid = threadIdx.x;
  int l = tid & 63, w = tid >> 6;
  int lr = l & 15, lg = l >> 4;
  int wr = (w >> 1) * 64, wc = (w & 1) * 64;

  // per-lane global staging addresses (row = w*32 + l/4, 16B chunk = l%4)
  const unsigned short* gA = A + (mbase + w * 32 + (l >> 2)) * 512 + (l & 3) * 8;
  const unsigned short* gB = BT + (size_t)(nbase + w * 32 + (l >> 2)) * 512 + (l & 3) * 8;
  // wave-uniform LDS bases (elements)
  unsigned short* lA = As + w * 1024;  // rows w*32.. ; +512 elems = +16 rows
  unsigned short* lB = Bs + w * 1024;

  f32x4 acc[4][4] = {};
  for (int k0 = 0; k0 < 512; k0 += 32) {
    GLDS16(gA + k0, lA);
    GLDS16(gA + k0 + 16 * 512, lA + 512);
    GLDS16(gB + k0, lB);
    GLDS16(gB + k0 + 16 * 512, lB + 512);
    asm volatile("s_waitcnt vmcnt(0)" ::: "memory");
    __syncthreads();
    bf16x8 af[4], bv8[4];
#pragma unroll
    for (int m = 0; m < 4; ++m)
      af[m] = *(const bf16x8*)&As[(wr + m * 16 + lr) * 32 + lg * 8];
#pragma unroll
    for (int n = 0; n < 4; ++n)
      bv8[n] = *(const bf16x8*)&Bs[(wc + n * 16 + lr) * 32 + lg * 8];
#pragma unroll
    for (int m = 0; m < 4; ++m)
#pragma unroll
      for (int n = 0; n < 4; ++n)
        acc[m][n] = __builtin_amdgcn_mfma_f32_16x16x32_bf16(af[m], bv8[n], acc[m][n], 0, 0, 0);
    __syncthreads();
  }
#pragma unroll
  for (int m = 0; m < 4; ++m) {
#pragma unroll
    for (int n = 0; n < 4; ++n) {
#pragma unroll
      for (int reg = 0; reg < 4; ++reg) {
        size_t row = mbase + wr + m * 16 + lg * 4 + reg;
        int col = nbase + wc + n * 16 + lr;
        float v = acc[m][n][reg] + bias[col];
        if constexpr (OUT_F32)
          ((float*)Out)[row * 512 + col] = v;
        else
          ((unsigned short*)Out)[row * 512 + col] = f2bf(v);
      }
    }
  }
}

// ---------------------------------------------------------------------------
// Fused attention (unchanged from passing R1)
// ---------------------------------------------------------------------------
__global__ __launch_bounds__(256) void attn_kernel(unsigned short* __restrict__ Q,
                                                   const unsigned short* __restrict__ Kp,
                                                   const unsigned short* __restrict__ Vt) {
  __shared__ __align__(16) unsigned short P[4][16][104];
  int tid = threadIdx.x;
  int l = tid & 63, w = tid >> 6;
  int lr = l & 15, lg = l >> 4;
  int bid = blockIdx.x;
  int qb = bid & 63;
  int h = (bid >> 6) & 7;
  int b = bid >> 9;

  for (int z = l; z < 16 * 16; z += 64) {
    P[w][z >> 4][80 + (z & 15)] = 0;
  }

  size_t qrow0 = (size_t)b * 4096 + qb * 64 + w * 16;
  const size_t qoff = (qrow0 + lr) * 512 + h * 64 + lg * 8;
  bf16x8 aq0 = *(const bf16x8*)(Q + qoff);
  bf16x8 aq1 = *(const bf16x8*)(Q + qoff + 32);

  const unsigned short* Kph = Kp + (size_t)(b * 8 + h) * 80 * 64;
  f32x4 s[5] = {};
#pragma unroll
  for (int t = 0; t < 5; ++t) {
    const unsigned short* kr = Kph + (t * 16 + lr) * 64 + lg * 8;
    bf16x8 b0 = *(const bf16x8*)kr;
    bf16x8 b1 = *(const bf16x8*)(kr + 32);
    s[t] = __builtin_amdgcn_mfma_f32_16x16x32_bf16(aq0, b0, s[t], 0, 0, 0);
    s[t] = __builtin_amdgcn_mfma_f32_16x16x32_bf16(aq1, b1, s[t], 0, 0, 0);
  }
  if (lr >= 13) {
    s[4][0] = -1e30f; s[4][1] = -1e30f; s[4][2] = -1e30f; s[4][3] = -1e30f;
  }

  float mx[4], sm[4];
#pragma unroll
  for (int r = 0; r < 4; ++r)
    mx[r] = fmaxf(fmaxf(fmaxf(s[0][r], s[1][r]), fmaxf(s[2][r], s[3][r])), s[4][r]);
#pragma unroll
  for (int d = 1; d < 16; d <<= 1)
#pragma unroll
    for (int r = 0; r < 4; ++r) mx[r] = fmaxf(mx[r], __shfl_xor(mx[r], d, 64));

  const float C = 0.125f * 1.44269504088896f;
  float p[5][4];
#pragma unroll
  for (int t = 0; t < 5; ++t)
#pragma unroll
    for (int r = 0; r < 4; ++r) p[t][r] = exp2f((s[t][r] - mx[r]) * C);
#pragma unroll
  for (int r = 0; r < 4; ++r)
    sm[r] = p[0][r] + p[1][r] + p[2][r] + p[3][r] + p[4][r];
#pragma unroll
  for (int d = 1; d < 16; d <<= 1)
#pragma unroll
    for (int r = 0; r < 4; ++r) sm[r] += __shfl_xor(sm[r], d, 64);
#pragma unroll
  for (int r = 0; r < 4; ++r) sm[r] = 1.0f / sm[r];
#pragma unroll
  for (int t = 0; t < 5; ++t)
#pragma unroll
    for (int r = 0; r < 4; ++r)
      P[w][lg * 4 + r][t * 16 + lr] = f2bf(p[t][r] * sm[r]);

  __syncthreads();

  const unsigned short* Vth = Vt + (size_t)(b * 8 + h) * 64 * 96;
  bf16x8 ap[3];
#pragma unroll
  for (int c = 0; c < 3; ++c) ap[c] = *(const bf16x8*)&P[w][lr][c * 32 + lg * 8];
#pragma unroll
  for (int ct = 0; ct < 4; ++ct) {
    f32x4 o = {};
#pragma unroll
    for (int c = 0; c < 3; ++c) {
      bf16x8 bv8 = *(const bf16x8*)(Vth + (size_t)(ct * 16 + lr) * 96 + c * 32 + lg * 8);
      o = __builtin_amdgcn_mfma_f32_16x16x32_bf16(ap[c], bv8, o, 0, 0, 0);
    }
#pragma unroll
    for (int reg = 0; reg < 4; ++reg) {
      Q[(qrow0 + lg * 4 + reg) * 512 + h * 64 + ct * 16 + lr] = f2bf(o[reg]);
    }
  }
}

// ---------------------------------------------------------------------------
// Workspace layout (bytes)
// ---------------------------------------------------------------------------
static const size_t OFF_Q   = 0;                         // 8*4096*512*2 = 33554432
static const size_t OFF_KP  = 33554432;                  // 8*8*80*64*2  = 655360
static const size_t OFF_VT  = OFF_KP + 655360;           // 8*8*64*96*2  = 786432
static const size_t OFF_WQT = OFF_VT + 786432;           // 512*512*2    = 524288
static const size_t OFF_WKT = OFF_WQT + 524288;          // 512*768*2    = 786432
static const size_t OFF_WVT = OFF_WKT + 786432;          // 512*768*2    = 786432
static const size_t OFF_WOT = OFF_WVT + 786432;          // 512*512*2    = 524288
static const size_t WS_NEEDED = OFF_WOT + 524288;        // 37617664

extern "C" void kernel_launch(void* const* d_in, const int* in_sizes, int n_in,
                              void* d_out, int out_size, void* d_ws, size_t ws_size,
                              hipStream_t stream) {
  (void)in_sizes; (void)n_in; (void)out_size;
  if (ws_size < WS_NEEDED) return;

  const float* latent  = (const float*)d_in[0];
  const float* context = (const float*)d_in[1];
  const float* wq = (const float*)d_in[2];
  const float* bq = (const float*)d_in[3];
  const float* wk = (const float*)d_in[4];
  const float* bk = (const float*)d_in[5];
  const float* wv = (const float*)d_in[6];
  const float* bv = (const float*)d_in[7];
  const float* wo = (const float*)d_in[8];
  const float* bo = (const float*)d_in[9];
  float* out = (float*)d_out;

  char* ws = (char*)d_ws;
  unsigned short* wsQ = (unsigned short*)(ws + OFF_Q);
  unsigned short* Kp  = (unsigned short*)(ws + OFF_KP);
  unsigned short* Vt  = (unsigned short*)(ws + OFF_VT);
  unsigned short* wqT = (unsigned short*)(ws + OFF_WQT);
  unsigned short* wkT = (unsigned short*)(ws + OFF_WKT);
  unsigned short* wvT = (unsigned short*)(ws + OFF_WVT);
  unsigned short* woT = (unsigned short*)(ws + OFF_WOT);

  // latent bf16 parked in d_out (first 33.5 MB of 67 MB); consumed by gemmQ,
  // then the whole d_out is rewritten by the final gemm.
  unsigned short* latBF = (unsigned short*)d_out;

  dim3 tb(32, 8);
  wtrans_kernel<<<dim3(16, 16), tb, 0, stream>>>(wq, wqT, 512, 512);
  wtrans_kernel<<<dim3(16, 24), tb, 0, stream>>>(wk, wkT, 768, 512);
  wtrans_kernel<<<dim3(16, 24), tb, 0, stream>>>(wv, wvT, 768, 512);
  wtrans_kernel<<<dim3(16, 16), tb, 0, stream>>>(wo, woT, 512, 512);

  hipMemsetAsync(ws + OFF_KP, 0, 655360 + 786432, stream);

  kv_proj_kernel<<<160, 256, 0, stream>>>(context, wkT, wvT, bk, bv, Kp, Vt);
  cvt_bf16_kernel<<<8192, 256, 0, stream>>>(latent, (unsigned int*)latBF);
  gemm512_glds_kernel<0><<<1024, 256, 0, stream>>>(latBF, wqT, bq, (void*)wsQ);
  attn_kernel<<<4096, 256, 0, stream>>>(wsQ, Kp, Vt);
  gemm512_glds_kernel<1><<<1024, 256, 0, stream>>>(wsQ, woT, bo, (void*)out);
}

// Round 3
// 147.851 us; speedup vs baseline: 1.1630x; 1.1298x over previous
//
#include <hip/hip_runtime.h>

// CrossAttention on MI355X (gfx950), round 3.
// B=8 SQ=4096 SKV=77 DE=512 DC=768 H=8 DH=64.
// R3 change: fuse attention into the Q-proj GEMM epilogue (wave-local:
// each wave's 64x64 GEMM quadrant = 64 q-rows x one head). Kills the 46us
// attn kernel + the 67MB wsQ round trip.

typedef __attribute__((ext_vector_type(8))) __bf16 bf16x8;
typedef __attribute__((ext_vector_type(4))) float f32x4;

#define DEVI static __device__ __forceinline__

typedef __attribute__((address_space(3))) void lds_void_t;
typedef const __attribute__((address_space(1))) void gbl_void_t;
#define GLDS16(gsrc, ldst) \
  __builtin_amdgcn_global_load_lds((gbl_void_t*)(gsrc), (lds_void_t*)(ldst), 16, 0, 0)

DEVI unsigned short f2bf(float f) {
  unsigned int u = __float_as_uint(f);
  u += 0x7FFFu + ((u >> 16) & 1u);   // round-to-nearest-even
  return (unsigned short)(u >> 16);
}

DEVI unsigned int pack2bf(float a, float b) {
  return (unsigned int)f2bf(a) | ((unsigned int)f2bf(b) << 16);
}

// ---------------------------------------------------------------------------
// latent fp32 -> bf16, 8 elems/thread
// ---------------------------------------------------------------------------
__global__ __launch_bounds__(256) void cvt_bf16_kernel(const float* __restrict__ in,
                                                       unsigned int* __restrict__ out4) {
  int i = blockIdx.x * 256 + threadIdx.x;
  const float4* in4 = (const float4*)in;
  float4 a = in4[2 * i];
  float4 b = in4[2 * i + 1];
  uint4 o;
  o.x = pack2bf(a.x, a.y);
  o.y = pack2bf(a.z, a.w);
  o.z = pack2bf(b.x, b.y);
  o.w = pack2bf(b.z, b.w);
  *(uint4*)(out4 + 4 * (size_t)i) = o;
}

// ---------------------------------------------------------------------------
// Weight transpose + fp32->bf16: in [K][N] f32 -> out [N][K] bf16
// ---------------------------------------------------------------------------
__global__ __launch_bounds__(256) void wtrans_kernel(const float* __restrict__ in,
                                                     unsigned short* __restrict__ out,
                                                     int K, int N) {
  __shared__ float tile[32][33];
  int n0 = blockIdx.x * 32, k0 = blockIdx.y * 32;
  int tx = threadIdx.x, ty = threadIdx.y;  // 32 x 8
#pragma unroll
  for (int j = 0; j < 4; ++j)
    tile[ty * 4 + j][tx] = in[(size_t)(k0 + ty * 4 + j) * N + n0 + tx];
  __syncthreads();
#pragma unroll
  for (int j = 0; j < 4; ++j)
    out[(size_t)(n0 + ty * 4 + j) * K + k0 + tx] = f2bf(tile[tx][ty * 4 + j]);
}

// ---------------------------------------------------------------------------
// K/V projection (unchanged, proven)
// ---------------------------------------------------------------------------
__global__ __launch_bounds__(256) void kv_proj_kernel(const float* __restrict__ ctx,
                                                      const unsigned short* __restrict__ wkT,
                                                      const unsigned short* __restrict__ wvT,
                                                      const float* __restrict__ bk,
                                                      const float* __restrict__ bv,
                                                      unsigned short* __restrict__ Kp,
                                                      unsigned short* __restrict__ Vt) {
  __shared__ __align__(16) unsigned short As[64][40];
  __shared__ __align__(16) unsigned short Bs[64][40];
  int bid = blockIdx.x;
  int sel = bid / 80;
  int rem = bid % 80;
  int mt = rem / 8, nt = rem % 8;
  const unsigned short* wT = sel ? wvT : wkT;
  const float* bias = sel ? bv : bk;
  int tid = threadIdx.x;
  int l = tid & 63, w = tid >> 6;
  int lr = l & 15, lg = l >> 4;

  f32x4 acc[4] = {};
  for (int k0 = 0; k0 < 768; k0 += 32) {
#pragma unroll
    for (int it = 0; it < 2; ++it) {
      int idx4 = it * 256 + tid;
      int r = idx4 >> 3, q4 = idx4 & 7;
      int m = mt * 64 + r;
      float4 v = {0.f, 0.f, 0.f, 0.f};
      if (m < 616) v = *(const float4*)(ctx + (size_t)m * 768 + k0 + q4 * 4);
      ushort4 o;
      o.x = f2bf(v.x); o.y = f2bf(v.y); o.z = f2bf(v.z); o.w = f2bf(v.w);
      *(ushort4*)&As[r][q4 * 4] = o;
    }
    {
      int c = tid >> 2, q8 = tid & 3;
      *(uint4*)&Bs[c][q8 * 8] =
          *(const uint4*)(wT + (size_t)(nt * 64 + c) * 768 + k0 + q8 * 8);
    }
    __syncthreads();
    bf16x8 a = *(const bf16x8*)&As[w * 16 + lr][lg * 8];
#pragma unroll
    for (int n = 0; n < 4; ++n) {
      bf16x8 bb = *(const bf16x8*)&Bs[n * 16 + lr][lg * 8];
      acc[n] = __builtin_amdgcn_mfma_f32_16x16x32_bf16(a, bb, acc[n], 0, 0, 0);
    }
    __syncthreads();
  }
#pragma unroll
  for (int n = 0; n < 4; ++n) {
#pragma unroll
    for (int reg = 0; reg < 4; ++reg) {
      int m = mt * 64 + w * 16 + lg * 4 + reg;
      if (m < 616) {
        int bI = m / 77, s = m % 77;
        int col = nt * 64 + n * 16 + lr;
        int h = col >> 6, d = col & 63;
        float v = acc[n][reg] + bias[col];
        if (sel == 0)
          Kp[(((size_t)(bI * 8 + h)) * 80 + s) * 64 + d] = f2bf(v);
        else
          Vt[(((size_t)(bI * 8 + h)) * 64 + d) * 96 + s] = f2bf(v);
      }
    }
  }
}

// ---------------------------------------------------------------------------
// FUSED Q-proj + attention.
// GEMM: latent_bf16 [32768][512] @ wqT [512][512] + bq -> Q tile 128x128
// (m97 structure: glds width-16, linear LDS, BK=32). Then, wave-local:
// each wave's 64x64 quadrant = 64 q-rows x one head. Quadrant -> LDS
// (C-layout -> A-layout), K/V frags from global (L2-hot), 4x 16-row
// attention units, O written bf16 to Oq (same [row][512] layout).
// LDS: union{As+Bs 16KB | Qw 4x64x72x2=36KB + P 4x16x104x2=13KB} = 50176B
// -> 3 blocks/CU.
// ---------------------------------------------------------------------------
__global__ __launch_bounds__(256, 3) void qproj_attn_kernel(
    const unsigned short* __restrict__ A, const unsigned short* __restrict__ BT,
    const float* __restrict__ bias, const unsigned short* __restrict__ Kp,
    const unsigned short* __restrict__ Vt, unsigned short* __restrict__ Oq) {
  __shared__ __align__(16) char smem[50176];
  unsigned short* As = (unsigned short*)smem;            // [128*32]
  unsigned short* Bs = (unsigned short*)(smem + 8192);   // [128*32]
  unsigned short* Qw = (unsigned short*)smem;            // [4][64][72]
  unsigned short* Pp = (unsigned short*)(smem + 36864);  // [4][16][104]

  int bid = blockIdx.x;
  size_t mbase = (size_t)(bid >> 2) * 128;
  int nbase = (bid & 3) * 128;
  int tid = threadIdx.x;
  int l = tid & 63, w = tid >> 6;
  int lr = l & 15, lg = l >> 4;
  int wr = (w >> 1) * 64, wc = (w & 1) * 64;

  const unsigned short* gA = A + (mbase + w * 32 + (l >> 2)) * 512 + (l & 3) * 8;
  const unsigned short* gB = BT + (size_t)(nbase + w * 32 + (l >> 2)) * 512 + (l & 3) * 8;
  unsigned short* lA = As + w * 1024;
  unsigned short* lB = Bs + w * 1024;

  f32x4 acc[4][4] = {};
  for (int k0 = 0; k0 < 512; k0 += 32) {
    GLDS16(gA + k0, lA);
    GLDS16(gA + k0 + 16 * 512, lA + 512);
    GLDS16(gB + k0, lB);
    GLDS16(gB + k0 + 16 * 512, lB + 512);
    asm volatile("s_waitcnt vmcnt(0)" ::: "memory");
    __syncthreads();
    bf16x8 af[4], bv8[4];
#pragma unroll
    for (int m = 0; m < 4; ++m)
      af[m] = *(const bf16x8*)&As[(wr + m * 16 + lr) * 32 + lg * 8];
#pragma unroll
    for (int n = 0; n < 4; ++n)
      bv8[n] = *(const bf16x8*)&Bs[(wc + n * 16 + lr) * 32 + lg * 8];
#pragma unroll
    for (int m = 0; m < 4; ++m)
#pragma unroll
      for (int n = 0; n < 4; ++n)
        acc[m][n] = __builtin_amdgcn_mfma_f32_16x16x32_bf16(af[m], bv8[n], acc[m][n], 0, 0, 0);
    __syncthreads();
  }

  // ---- epilogue: Q quadrant (bias added, bf16) into wave-private LDS ----
  unsigned short* Qme = Qw + w * (64 * 72);
  float bb[4];
#pragma unroll
  for (int n = 0; n < 4; ++n) bb[n] = bias[nbase + wc + n * 16 + lr];
#pragma unroll
  for (int m = 0; m < 4; ++m)
#pragma unroll
    for (int n = 0; n < 4; ++n)
#pragma unroll
      for (int reg = 0; reg < 4; ++reg)
        Qme[(m * 16 + lg * 4 + reg) * 72 + n * 16 + lr] = f2bf(acc[m][n][reg] + bb[n]);

  // zero P pad cols [80,96) (read by PV, multiplied by zero V rows; must be finite)
  unsigned short* Pme = Pp + w * (16 * 104);
  for (int z = l; z < 256; z += 64) Pme[(z >> 4) * 104 + 80 + (z & 15)] = 0;

  asm volatile("s_waitcnt lgkmcnt(0)" ::: "memory");
  __builtin_amdgcn_sched_barrier(0);

  // ---- wave-local attention: 64 q-rows x head h ----
  int b = (int)(mbase >> 12);
  int h = (bid & 3) * 2 + (w & 1);
  const unsigned short* Kph = Kp + (size_t)(b * 8 + h) * (80 * 64);
  const unsigned short* Vth = Vt + (size_t)(b * 8 + h) * (64 * 96);

  bf16x8 kf[5][2];
#pragma unroll
  for (int t = 0; t < 5; ++t) {
    const unsigned short* kr = Kph + (t * 16 + lr) * 64 + lg * 8;
    kf[t][0] = *(const bf16x8*)kr;
    kf[t][1] = *(const bf16x8*)(kr + 32);
  }

  const float C = 0.125f * 1.44269504088896f;  // 1/sqrt(64) * log2(e)
#pragma unroll
  for (int rg = 0; rg < 4; ++rg) {
    bf16x8 aq0 = *(const bf16x8*)&Qme[(rg * 16 + lr) * 72 + lg * 8];
    bf16x8 aq1 = *(const bf16x8*)&Qme[(rg * 16 + lr) * 72 + 32 + lg * 8];
    f32x4 s[5] = {};
#pragma unroll
    for (int t = 0; t < 5; ++t) {
      s[t] = __builtin_amdgcn_mfma_f32_16x16x32_bf16(aq0, kf[t][0], s[t], 0, 0, 0);
      s[t] = __builtin_amdgcn_mfma_f32_16x16x32_bf16(aq1, kf[t][1], s[t], 0, 0, 0);
    }
    if (lr >= 13) {  // cols 64+lr >= 77 are pad
      s[4][0] = -1e30f; s[4][1] = -1e30f; s[4][2] = -1e30f; s[4][3] = -1e30f;
    }
    float mx[4], sm[4];
#pragma unroll
    for (int r = 0; r < 4; ++r)
      mx[r] = fmaxf(fmaxf(fmaxf(s[0][r], s[1][r]), fmaxf(s[2][r], s[3][r])), s[4][r]);
#pragma unroll
    for (int d = 1; d < 16; d <<= 1)
#pragma unroll
      for (int r = 0; r < 4; ++r) mx[r] = fmaxf(mx[r], __shfl_xor(mx[r], d, 64));
    float p[5][4];
#pragma unroll
    for (int t = 0; t < 5; ++t)
#pragma unroll
      for (int r = 0; r < 4; ++r) p[t][r] = exp2f((s[t][r] - mx[r]) * C);
#pragma unroll
    for (int r = 0; r < 4; ++r)
      sm[r] = p[0][r] + p[1][r] + p[2][r] + p[3][r] + p[4][r];
#pragma unroll
    for (int d = 1; d < 16; d <<= 1)
#pragma unroll
      for (int r = 0; r < 4; ++r) sm[r] += __shfl_xor(sm[r], d, 64);
#pragma unroll
    for (int r = 0; r < 4; ++r) sm[r] = 1.0f / sm[r];
#pragma unroll
    for (int t = 0; t < 5; ++t)
#pragma unroll
      for (int r = 0; r < 4; ++r)
        Pme[(lg * 4 + r) * 104 + t * 16 + lr] = f2bf(p[t][r] * sm[r]);

    asm volatile("s_waitcnt lgkmcnt(0)" ::: "memory");
    __builtin_amdgcn_sched_barrier(0);

    bf16x8 ap[3];
#pragma unroll
    for (int c = 0; c < 3; ++c) ap[c] = *(const bf16x8*)&Pme[lr * 104 + c * 32 + lg * 8];
#pragma unroll
    for (int ct = 0; ct < 4; ++ct) {
      f32x4 o = {};
#pragma unroll
      for (int c = 0; c < 3; ++c) {
        bf16x8 vv = *(const bf16x8*)(Vth + (size_t)(ct * 16 + lr) * 96 + c * 32 + lg * 8);
        o = __builtin_amdgcn_mfma_f32_16x16x32_bf16(ap[c], vv, o, 0, 0, 0);
      }
#pragma unroll
      for (int reg = 0; reg < 4; ++reg)
        Oq[(mbase + wr + rg * 16 + lg * 4 + reg) * 512 + nbase + wc + ct * 16 + lr] =
            f2bf(o[reg]);
    }
  }
}

// ---------------------------------------------------------------------------
// m97-style GEMM for O-proj: A [32768][512] bf16 @ woT [512][512] + bo -> f32
// ---------------------------------------------------------------------------
template <int OUT_F32>
__global__ __launch_bounds__(256) void gemm512_glds_kernel(
    const unsigned short* __restrict__ A, const unsigned short* __restrict__ BT,
    const float* __restrict__ bias, void* __restrict__ Out) {
  __shared__ __align__(16) unsigned short As[128 * 32];
  __shared__ __align__(16) unsigned short Bs[128 * 32];
  int bid = blockIdx.x;
  size_t mbase = (size_t)(bid >> 2) * 128;
  int nbase = (bid & 3) * 128;
  int tid = threadIdx.x;
  int l = tid & 63, w = tid >> 6;
  int lr = l & 15, lg = l >> 4;
  int wr = (w >> 1) * 64, wc = (w & 1) * 64;

  const unsigned short* gA = A + (mbase + w * 32 + (l >> 2)) * 512 + (l & 3) * 8;
  const unsigned short* gB = BT + (size_t)(nbase + w * 32 + (l >> 2)) * 512 + (l & 3) * 8;
  unsigned short* lA = As + w * 1024;
  unsigned short* lB = Bs + w * 1024;

  f32x4 acc[4][4] = {};
  for (int k0 = 0; k0 < 512; k0 += 32) {
    GLDS16(gA + k0, lA);
    GLDS16(gA + k0 + 16 * 512, lA + 512);
    GLDS16(gB + k0, lB);
    GLDS16(gB + k0 + 16 * 512, lB + 512);
    asm volatile("s_waitcnt vmcnt(0)" ::: "memory");
    __syncthreads();
    bf16x8 af[4], bv8[4];
#pragma unroll
    for (int m = 0; m < 4; ++m)
      af[m] = *(const bf16x8*)&As[(wr + m * 16 + lr) * 32 + lg * 8];
#pragma unroll
    for (int n = 0; n < 4; ++n)
      bv8[n] = *(const bf16x8*)&Bs[(wc + n * 16 + lr) * 32 + lg * 8];
#pragma unroll
    for (int m = 0; m < 4; ++m)
#pragma unroll
      for (int n = 0; n < 4; ++n)
        acc[m][n] = __builtin_amdgcn_mfma_f32_16x16x32_bf16(af[m], bv8[n], acc[m][n], 0, 0, 0);
    __syncthreads();
  }
#pragma unroll
  for (int m = 0; m < 4; ++m) {
#pragma unroll
    for (int n = 0; n < 4; ++n) {
#pragma unroll
      for (int reg = 0; reg < 4; ++reg) {
        size_t row = mbase + wr + m * 16 + lg * 4 + reg;
        int col = nbase + wc + n * 16 + lr;
        float v = acc[m][n][reg] + bias[col];
        if constexpr (OUT_F32)
          ((float*)Out)[row * 512 + col] = v;
        else
          ((unsigned short*)Out)[row * 512 + col] = f2bf(v);
      }
    }
  }
}

// ---------------------------------------------------------------------------
// Workspace layout (bytes)
// ---------------------------------------------------------------------------
static const size_t OFF_Q   = 0;                         // 8*4096*512*2 = 33554432
static const size_t OFF_KP  = 33554432;                  // 8*8*80*64*2  = 655360
static const size_t OFF_VT  = OFF_KP + 655360;           // 8*8*64*96*2  = 786432
static const size_t OFF_WQT = OFF_VT + 786432;           // 512*512*2
static const size_t OFF_WKT = OFF_WQT + 524288;          // 512*768*2
static const size_t OFF_WVT = OFF_WKT + 786432;          // 512*768*2
static const size_t OFF_WOT = OFF_WVT + 786432;          // 512*512*2
static const size_t WS_NEEDED = OFF_WOT + 524288;        // 37617664

extern "C" void kernel_launch(void* const* d_in, const int* in_sizes, int n_in,
                              void* d_out, int out_size, void* d_ws, size_t ws_size,
                              hipStream_t stream) {
  (void)in_sizes; (void)n_in; (void)out_size;
  if (ws_size < WS_NEEDED) return;

  const float* latent  = (const float*)d_in[0];
  const float* context = (const float*)d_in[1];
  const float* wq = (const float*)d_in[2];
  const float* bq = (const float*)d_in[3];
  const float* wk = (const float*)d_in[4];
  const float* bk = (const float*)d_in[5];
  const float* wv = (const float*)d_in[6];
  const float* bv = (const float*)d_in[7];
  const float* wo = (const float*)d_in[8];
  const float* bo = (const float*)d_in[9];
  float* out = (float*)d_out;

  char* ws = (char*)d_ws;
  unsigned short* wsQ = (unsigned short*)(ws + OFF_Q);   // attn output (bf16)
  unsigned short* Kp  = (unsigned short*)(ws + OFF_KP);
  unsigned short* Vt  = (unsigned short*)(ws + OFF_VT);
  unsigned short* wqT = (unsigned short*)(ws + OFF_WQT);
  unsigned short* wkT = (unsigned short*)(ws + OFF_WKT);
  unsigned short* wvT = (unsigned short*)(ws + OFF_WVT);
  unsigned short* woT = (unsigned short*)(ws + OFF_WOT);

  // latent bf16 parked in d_out; consumed by fused kernel, then d_out is
  // fully rewritten by the final GEMM.
  unsigned short* latBF = (unsigned short*)d_out;

  dim3 tb(32, 8);
  wtrans_kernel<<<dim3(16, 16), tb, 0, stream>>>(wq, wqT, 512, 512);
  wtrans_kernel<<<dim3(16, 24), tb, 0, stream>>>(wk, wkT, 768, 512);
  wtrans_kernel<<<dim3(16, 24), tb, 0, stream>>>(wv, wvT, 768, 512);
  wtrans_kernel<<<dim3(16, 16), tb, 0, stream>>>(wo, woT, 512, 512);

  hipMemsetAsync(ws + OFF_KP, 0, 655360 + 786432, stream);

  kv_proj_kernel<<<160, 256, 0, stream>>>(context, wkT, wvT, bk, bv, Kp, Vt);
  cvt_bf16_kernel<<<8192, 256, 0, stream>>>(latent, (unsigned int*)latBF);
  qproj_attn_kernel<<<1024, 256, 0, stream>>>(latBF, wqT, bq, Kp, Vt, wsQ);
  gemm512_glds_kernel<1><<<1024, 256, 0, stream>>>(wsQ, woT, bo, (void*)out);
}

// Round 4
// 138.457 us; speedup vs baseline: 1.2419x; 1.0678x over previous
//
#include <hip/hip_runtime.h>

// CrossAttention on MI355X (gfx950), round 4.
// B=8 SQ=4096 SKV=77 DE=512 DC=768 H=8 DH=64.
// R4: (1) fuse fp32->bf16 latent conversion into qproj A-staging (cvt kernel
// gone); (2) Q-frags preloaded to regs + P overlaid into dead Qw LDS ->
// 36864B LDS, launch_bounds(256,4) for 4 blocks/CU; (3) attn tail
// de-serialized (QK(rg+1) overlapped with softmax/PV(rg)); (4) 4 wtrans
// launches merged into 1.

typedef __attribute__((ext_vector_type(8))) __bf16 bf16x8;
typedef __attribute__((ext_vector_type(4))) float f32x4;

#define DEVI static __device__ __forceinline__

typedef __attribute__((address_space(3))) void lds_void_t;
typedef const __attribute__((address_space(1))) void gbl_void_t;
#define GLDS16(gsrc, ldst) \
  __builtin_amdgcn_global_load_lds((gbl_void_t*)(gsrc), (lds_void_t*)(ldst), 16, 0, 0)

DEVI unsigned short f2bf(float f) {
  unsigned int u = __float_as_uint(f);
  u += 0x7FFFu + ((u >> 16) & 1u);   // round-to-nearest-even
  return (unsigned short)(u >> 16);
}

DEVI unsigned int pack2bf(float a, float b) {
  return (unsigned int)f2bf(a) | ((unsigned int)f2bf(b) << 16);
}

// ---------------------------------------------------------------------------
// All 4 weight transposes in one launch. in [K][N=512] f32 -> out [N][K] bf16.
// blocks: wq 256 | wk 384 | wv 384 | wo 256  (32x32 tiles, threads 32x8)
// ---------------------------------------------------------------------------
__global__ __launch_bounds__(256) void wtrans_all_kernel(
    const float* __restrict__ wq, const float* __restrict__ wk,
    const float* __restrict__ wv, const float* __restrict__ wo,
    unsigned short* __restrict__ wqT, unsigned short* __restrict__ wkT,
    unsigned short* __restrict__ wvT, unsigned short* __restrict__ woT) {
  __shared__ float tile[32][33];
  int bid = blockIdx.x;
  const float* in;
  unsigned short* out;
  int K, r;
  if (bid < 256)       { in = wq; out = wqT; K = 512; r = bid; }
  else if (bid < 640)  { in = wk; out = wkT; K = 768; r = bid - 256; }
  else if (bid < 1024) { in = wv; out = wvT; K = 768; r = bid - 640; }
  else                 { in = wo; out = woT; K = 512; r = bid - 1024; }
  int n0 = (r & 15) * 32, k0 = (r >> 4) * 32;
  int tx = threadIdx.x, ty = threadIdx.y;
#pragma unroll
  for (int j = 0; j < 4; ++j)
    tile[ty * 4 + j][tx] = in[(size_t)(k0 + ty * 4 + j) * 512 + n0 + tx];
  __syncthreads();
#pragma unroll
  for (int j = 0; j < 4; ++j)
    out[(size_t)(n0 + ty * 4 + j) * K + k0 + tx] = f2bf(tile[tx][ty * 4 + j]);
}

// ---------------------------------------------------------------------------
// K/V projection (unchanged, proven)
// ---------------------------------------------------------------------------
__global__ __launch_bounds__(256) void kv_proj_kernel(const float* __restrict__ ctx,
                                                      const unsigned short* __restrict__ wkT,
                                                      const unsigned short* __restrict__ wvT,
                                                      const float* __restrict__ bk,
                                                      const float* __restrict__ bv,
                                                      unsigned short* __restrict__ Kp,
                                                      unsigned short* __restrict__ Vt) {
  __shared__ __align__(16) unsigned short As[64][40];
  __shared__ __align__(16) unsigned short Bs[64][40];
  int bid = blockIdx.x;
  int sel = bid / 80;
  int rem = bid % 80;
  int mt = rem / 8, nt = rem % 8;
  const unsigned short* wT = sel ? wvT : wkT;
  const float* bias = sel ? bv : bk;
  int tid = threadIdx.x;
  int l = tid & 63, w = tid >> 6;
  int lr = l & 15, lg = l >> 4;

  f32x4 acc[4] = {};
  for (int k0 = 0; k0 < 768; k0 += 32) {
#pragma unroll
    for (int it = 0; it < 2; ++it) {
      int idx4 = it * 256 + tid;
      int r = idx4 >> 3, q4 = idx4 & 7;
      int m = mt * 64 + r;
      float4 v = {0.f, 0.f, 0.f, 0.f};
      if (m < 616) v = *(const float4*)(ctx + (size_t)m * 768 + k0 + q4 * 4);
      ushort4 o;
      o.x = f2bf(v.x); o.y = f2bf(v.y); o.z = f2bf(v.z); o.w = f2bf(v.w);
      *(ushort4*)&As[r][q4 * 4] = o;
    }
    {
      int c = tid >> 2, q8 = tid & 3;
      *(uint4*)&Bs[c][q8 * 8] =
          *(const uint4*)(wT + (size_t)(nt * 64 + c) * 768 + k0 + q8 * 8);
    }
    __syncthreads();
    bf16x8 a = *(const bf16x8*)&As[w * 16 + lr][lg * 8];
#pragma unroll
    for (int n = 0; n < 4; ++n) {
      bf16x8 bb = *(const bf16x8*)&Bs[n * 16 + lr][lg * 8];
      acc[n] = __builtin_amdgcn_mfma_f32_16x16x32_bf16(a, bb, acc[n], 0, 0, 0);
    }
    __syncthreads();
  }
#pragma unroll
  for (int n = 0; n < 4; ++n) {
#pragma unroll
    for (int reg = 0; reg < 4; ++reg) {
      int m = mt * 64 + w * 16 + lg * 4 + reg;
      if (m < 616) {
        int bI = m / 77, s = m % 77;
        int col = nt * 64 + n * 16 + lr;
        int h = col >> 6, d = col & 63;
        float v = acc[n][reg] + bias[col];
        if (sel == 0)
          Kp[(((size_t)(bI * 8 + h)) * 80 + s) * 64 + d] = f2bf(v);
        else
          Vt[(((size_t)(bI * 8 + h)) * 64 + d) * 96 + s] = f2bf(v);
      }
    }
  }
}

// ---------------------------------------------------------------------------
// FUSED Q-proj + attention, v2.
// A = latent fp32 [32768][512], converted to bf16 during staging (chunk-linear
// ds_write: lane t -> LDS byte t*16 => conflict-free). B via glds width-16.
// Epilogue: Q quadrant -> LDS (transpose) -> Q frags preloaded to REGS ->
// barrier -> P buffer overlaid into dead Qw region. Attn tail: QK(rg+1)
// pure-reg MFMA issued between P-write(rg) and PV(rg) for VALU/MFMA overlap.
// LDS = 36864 B -> 4 blocks/CU with VGPR<=128.
// ---------------------------------------------------------------------------
__global__ __launch_bounds__(256, 4) void qproj_attn_kernel(
    const float* __restrict__ A32, const unsigned short* __restrict__ BT,
    const float* __restrict__ bias, const unsigned short* __restrict__ Kp,
    const unsigned short* __restrict__ Vt, unsigned short* __restrict__ Oq) {
  __shared__ __align__(16) char smem[36864];
  unsigned short* As = (unsigned short*)smem;            // [128*32] (GEMM)
  unsigned short* Bs = (unsigned short*)(smem + 8192);   // [128*32] (GEMM)
  unsigned short* Qw = (unsigned short*)smem;            // [4][64][72] (epilogue)

  int bid = blockIdx.x;
  size_t mbase = (size_t)(bid >> 2) * 128;
  int nbase = (bid & 3) * 128;
  int tid = threadIdx.x;
  int l = tid & 63, w = tid >> 6;
  int lr = l & 15, lg = l >> 4;
  int wr = (w >> 1) * 64, wc = (w & 1) * 64;

  // A staging: thread t owns chunks t and t+256 (chunk c = 8 bf16 at LDS
  // elem c*8; source row c>>2, k-offset (c&3)*8).
  const float* pA0 = A32 + (mbase + (tid >> 2)) * 512 + (tid & 3) * 8;
  const float* pA1 = pA0 + (size_t)64 * 512;
  const unsigned short* gB = BT + (size_t)(nbase + w * 32 + (l >> 2)) * 512 + (l & 3) * 8;
  unsigned short* lB = Bs + w * 1024;

  f32x4 acc[4][4] = {};
  for (int k0 = 0; k0 < 512; k0 += 32) {
    GLDS16(gB + k0, lB);
    GLDS16(gB + k0 + 16 * 512, lB + 512);
    float4 x0 = *(const float4*)(pA0 + k0);
    float4 x1 = *(const float4*)(pA0 + k0 + 4);
    float4 x2 = *(const float4*)(pA1 + k0);
    float4 x3 = *(const float4*)(pA1 + k0 + 4);
    uint4 u0, u1;
    u0.x = pack2bf(x0.x, x0.y); u0.y = pack2bf(x0.z, x0.w);
    u0.z = pack2bf(x1.x, x1.y); u0.w = pack2bf(x1.z, x1.w);
    u1.x = pack2bf(x2.x, x2.y); u1.y = pack2bf(x2.z, x2.w);
    u1.z = pack2bf(x3.x, x3.y); u1.w = pack2bf(x3.z, x3.w);
    *(uint4*)&As[tid * 8] = u0;
    *(uint4*)&As[tid * 8 + 2048] = u1;
    asm volatile("s_waitcnt vmcnt(0)" ::: "memory");
    __syncthreads();
    bf16x8 af[4], bv8[4];
#pragma unroll
    for (int m = 0; m < 4; ++m)
      af[m] = *(const bf16x8*)&As[(wr + m * 16 + lr) * 32 + lg * 8];
#pragma unroll
    for (int n = 0; n < 4; ++n)
      bv8[n] = *(const bf16x8*)&Bs[(wc + n * 16 + lr) * 32 + lg * 8];
#pragma unroll
    for (int m = 0; m < 4; ++m)
#pragma unroll
      for (int n = 0; n < 4; ++n)
        acc[m][n] = __builtin_amdgcn_mfma_f32_16x16x32_bf16(af[m], bv8[n], acc[m][n], 0, 0, 0);
    __syncthreads();
  }

  // ---- epilogue: Q quadrant -> wave-private LDS (transpose), +bias ----
  unsigned short* Qme = Qw + w * (64 * 72);
  float bb[4];
#pragma unroll
  for (int n = 0; n < 4; ++n) bb[n] = bias[nbase + wc + n * 16 + lr];
#pragma unroll
  for (int m = 0; m < 4; ++m)
#pragma unroll
    for (int n = 0; n < 4; ++n)
#pragma unroll
      for (int reg = 0; reg < 4; ++reg)
        Qme[(m * 16 + lg * 4 + reg) * 72 + n * 16 + lr] = f2bf(acc[m][n][reg] + bb[n]);

  // preload ALL Q frags to regs (wave-local LDS RAW: compiler orders)
  bf16x8 qf[4][2];
#pragma unroll
  for (int rg = 0; rg < 4; ++rg) {
    qf[rg][0] = *(const bf16x8*)&Qme[(rg * 16 + lr) * 72 + lg * 8];
    qf[rg][1] = *(const bf16x8*)&Qme[(rg * 16 + lr) * 72 + 32 + lg * 8];
  }
  __syncthreads();  // all waves done with Qw -> safe to overlay P

  // P overlaid at smem base: per-wave 16 rows x 104 cols bf16 (3328 B)
  unsigned short* Pme = (unsigned short*)smem + w * 1664;
  for (int z = l; z < 256; z += 64) Pme[(z >> 4) * 104 + 80 + (z & 15)] = 0;

  // ---- wave-local attention: 64 q-rows x head h ----
  int b = (int)(mbase >> 12);
  int h = (bid & 3) * 2 + (w & 1);
  const unsigned short* Kph = Kp + (size_t)(b * 8 + h) * (80 * 64);
  const unsigned short* Vth = Vt + (size_t)(b * 8 + h) * (64 * 96);

  const float C = 0.125f * 1.44269504088896f;  // 1/sqrt(64) * log2(e)

  // QK unit: pure-reg A-operand; K frags loaded per-call (L1-resident, 10KB)
  auto QK = [&](int rg, f32x4* s) {
#pragma unroll
    for (int t = 0; t < 5; ++t) {
      const unsigned short* kr = Kph + (t * 16 + lr) * 64 + lg * 8;
      bf16x8 k0 = *(const bf16x8*)kr;
      bf16x8 k1 = *(const bf16x8*)(kr + 32);
      s[t] = __builtin_amdgcn_mfma_f32_16x16x32_bf16(qf[rg][0], k0, s[t], 0, 0, 0);
      s[t] = __builtin_amdgcn_mfma_f32_16x16x32_bf16(qf[rg][1], k1, s[t], 0, 0, 0);
    }
    if (lr >= 13) {  // cols 64+lr >= 77 are pad
      s[4][0] = -1e30f; s[4][1] = -1e30f; s[4][2] = -1e30f; s[4][3] = -1e30f;
    }
  };

  f32x4 sc[5] = {};
  QK(0, sc);
#pragma unroll
  for (int rg = 0; rg < 4; ++rg) {
    // softmax over 77 cols (rows = lg*4+r, cols spread over lr x 5 tiles)
    float mx[4], sm[4];
#pragma unroll
    for (int r = 0; r < 4; ++r)
      mx[r] = fmaxf(fmaxf(fmaxf(sc[0][r], sc[1][r]), fmaxf(sc[2][r], sc[3][r])), sc[4][r]);
#pragma unroll
    for (int d = 1; d < 16; d <<= 1)
#pragma unroll
      for (int r = 0; r < 4; ++r) mx[r] = fmaxf(mx[r], __shfl_xor(mx[r], d, 64));
    float p[5][4];
#pragma unroll
    for (int t = 0; t < 5; ++t)
#pragma unroll
      for (int r = 0; r < 4; ++r) p[t][r] = exp2f((sc[t][r] - mx[r]) * C);
#pragma unroll
    for (int r = 0; r < 4; ++r)
      sm[r] = p[0][r] + p[1][r] + p[2][r] + p[3][r] + p[4][r];
#pragma unroll
    for (int d = 1; d < 16; d <<= 1)
#pragma unroll
      for (int r = 0; r < 4; ++r) sm[r] += __shfl_xor(sm[r], d, 64);
#pragma unroll
    for (int r = 0; r < 4; ++r) sm[r] = 1.0f / sm[r];
#pragma unroll
    for (int t = 0; t < 5; ++t)
#pragma unroll
      for (int r = 0; r < 4; ++r)
        Pme[(lg * 4 + r) * 104 + t * 16 + lr] = f2bf(p[t][r] * sm[r]);

    // next QK: pure-reg MFMA + global K loads; no LDS dep -> scheduler can
    // overlap it with the softmax VALU above and the PV below.
    f32x4 sn[5] = {};
    if (rg < 3) QK(rg + 1, sn);

    // PV: A = P [16 x 96] (LDS, ordered after the P-writes), B = Vt rows
    bf16x8 ap[3];
#pragma unroll
    for (int c = 0; c < 3; ++c) ap[c] = *(const bf16x8*)&Pme[lr * 104 + c * 32 + lg * 8];
#pragma unroll
    for (int ct = 0; ct < 4; ++ct) {
      f32x4 o = {};
#pragma unroll
      for (int c = 0; c < 3; ++c) {
        bf16x8 vv = *(const bf16x8*)(Vth + (size_t)(ct * 16 + lr) * 96 + c * 32 + lg * 8);
        o = __builtin_amdgcn_mfma_f32_16x16x32_bf16(ap[c], vv, o, 0, 0, 0);
      }
#pragma unroll
      for (int reg = 0; reg < 4; ++reg)
        Oq[(mbase + wr + rg * 16 + lg * 4 + reg) * 512 + nbase + wc + ct * 16 + lr] =
            f2bf(o[reg]);
    }
#pragma unroll
    for (int t = 0; t < 5; ++t) sc[t] = sn[t];
  }
}

// ---------------------------------------------------------------------------
// m97-style GEMM for O-proj: A [32768][512] bf16 @ woT [512][512] + bo -> f32
// ---------------------------------------------------------------------------
__global__ __launch_bounds__(256) void gemm512_glds_kernel(
    const unsigned short* __restrict__ A, const unsigned short* __restrict__ BT,
    const float* __restrict__ bias, float* __restrict__ Out) {
  __shared__ __align__(16) unsigned short As[128 * 32];
  __shared__ __align__(16) unsigned short Bs[128 * 32];
  int bid = blockIdx.x;
  size_t mbase = (size_t)(bid >> 2) * 128;
  int nbase = (bid & 3) * 128;
  int tid = threadIdx.x;
  int l = tid & 63, w = tid >> 6;
  int lr = l & 15, lg = l >> 4;
  int wr = (w >> 1) * 64, wc = (w & 1) * 64;

  const unsigned short* gA = A + (mbase + w * 32 + (l >> 2)) * 512 + (l & 3) * 8;
  const unsigned short* gB = BT + (size_t)(nbase + w * 32 + (l >> 2)) * 512 + (l & 3) * 8;
  unsigned short* lA = As + w * 1024;
  unsigned short* lB = Bs + w * 1024;

  f32x4 acc[4][4] = {};
  for (int k0 = 0; k0 < 512; k0 += 32) {
    GLDS16(gA + k0, lA);
    GLDS16(gA + k0 + 16 * 512, lA + 512);
    GLDS16(gB + k0, lB);
    GLDS16(gB + k0 + 16 * 512, lB + 512);
    asm volatile("s_waitcnt vmcnt(0)" ::: "memory");
    __syncthreads();
    bf16x8 af[4], bv8[4];
#pragma unroll
    for (int m = 0; m < 4; ++m)
      af[m] = *(const bf16x8*)&As[(wr + m * 16 + lr) * 32 + lg * 8];
#pragma unroll
    for (int n = 0; n < 4; ++n)
      bv8[n] = *(const bf16x8*)&Bs[(wc + n * 16 + lr) * 32 + lg * 8];
#pragma unroll
    for (int m = 0; m < 4; ++m)
#pragma unroll
      for (int n = 0; n < 4; ++n)
        acc[m][n] = __builtin_amdgcn_mfma_f32_16x16x32_bf16(af[m], bv8[n], acc[m][n], 0, 0, 0);
    __syncthreads();
  }
#pragma unroll
  for (int m = 0; m < 4; ++m) {
#pragma unroll
    for (int n = 0; n < 4; ++n) {
#pragma unroll
      for (int reg = 0; reg < 4; ++reg) {
        size_t row = mbase + wr + m * 16 + lg * 4 + reg;
        int col = nbase + wc + n * 16 + lr;
        Out[row * 512 + col] = acc[m][n][reg] + bias[col];
      }
    }
  }
}

// ---------------------------------------------------------------------------
// Workspace layout (bytes)
// ---------------------------------------------------------------------------
static const size_t OFF_Q   = 0;                         // 8*4096*512*2 = 33554432
static const size_t OFF_KP  = 33554432;                  // 8*8*80*64*2  = 655360
static const size_t OFF_VT  = OFF_KP + 655360;           // 8*8*64*96*2  = 786432
static const size_t OFF_WQT = OFF_VT + 786432;           // 512*512*2
static const size_t OFF_WKT = OFF_WQT + 524288;          // 512*768*2
static const size_t OFF_WVT = OFF_WKT + 786432;          // 512*768*2
static const size_t OFF_WOT = OFF_WVT + 786432;          // 512*512*2
static const size_t WS_NEEDED = OFF_WOT + 524288;        // 37617664

extern "C" void kernel_launch(void* const* d_in, const int* in_sizes, int n_in,
                              void* d_out, int out_size, void* d_ws, size_t ws_size,
                              hipStream_t stream) {
  (void)in_sizes; (void)n_in; (void)out_size;
  if (ws_size < WS_NEEDED) return;

  const float* latent  = (const float*)d_in[0];
  const float* context = (const float*)d_in[1];
  const float* wq = (const float*)d_in[2];
  const float* bq = (const float*)d_in[3];
  const float* wk = (const float*)d_in[4];
  const float* bk = (const float*)d_in[5];
  const float* wv = (const float*)d_in[6];
  const float* bv = (const float*)d_in[7];
  const float* wo = (const float*)d_in[8];
  const float* bo = (const float*)d_in[9];
  float* out = (float*)d_out;

  char* ws = (char*)d_ws;
  unsigned short* wsQ = (unsigned short*)(ws + OFF_Q);   // attn output (bf16)
  unsigned short* Kp  = (unsigned short*)(ws + OFF_KP);
  unsigned short* Vt  = (unsigned short*)(ws + OFF_VT);
  unsigned short* wqT = (unsigned short*)(ws + OFF_WQT);
  unsigned short* wkT = (unsigned short*)(ws + OFF_WKT);
  unsigned short* wvT = (unsigned short*)(ws + OFF_WVT);
  unsigned short* woT = (unsigned short*)(ws + OFF_WOT);

  wtrans_all_kernel<<<1280, dim3(32, 8), 0, stream>>>(wq, wk, wv, wo,
                                                      wqT, wkT, wvT, woT);
  hipMemsetAsync(ws + OFF_KP, 0, 655360 + 786432, stream);
  kv_proj_kernel<<<160, 256, 0, stream>>>(context, wkT, wvT, bk, bv, Kp, Vt);
  qproj_attn_kernel<<<1024, 256, 0, stream>>>(latent, wqT, bq, Kp, Vt, wsQ);
  gemm512_glds_kernel<<<1024, 256, 0, stream>>>(wsQ, woT, bo, out);
}

// Round 5
// 122.346 us; speedup vs baseline: 1.4054x; 1.1317x over previous
//
#include <hip/hip_runtime.h>

// CrossAttention on MI355X (gfx950), round 5.
// B=8 SQ=4096 SKV=77 DE=512 DC=768 H=8 DH=64.
// R5: (1) XCD-bijective block swizzle on qproj+ogemm (A-panel siblings share
// one XCD L2 -> A fetched once, not 4x); (2) 2-phase double-buffered K-loop
// in qproj (stage k+1 issued before MFMA of k; LDS 2x(8+8)KB=32KB, still
// 4 blocks/CU under the 36864B attn overlay).

typedef __attribute__((ext_vector_type(8))) __bf16 bf16x8;
typedef __attribute__((ext_vector_type(4))) float f32x4;

#define DEVI static __device__ __forceinline__

typedef __attribute__((address_space(3))) void lds_void_t;
typedef const __attribute__((address_space(1))) void gbl_void_t;
#define GLDS16(gsrc, ldst) \
  __builtin_amdgcn_global_load_lds((gbl_void_t*)(gsrc), (lds_void_t*)(ldst), 16, 0, 0)

DEVI unsigned short f2bf(float f) {
  unsigned int u = __float_as_uint(f);
  u += 0x7FFFu + ((u >> 16) & 1u);   // round-to-nearest-even
  return (unsigned short)(u >> 16);
}

DEVI unsigned int pack2bf(float a, float b) {
  return (unsigned int)f2bf(a) | ((unsigned int)f2bf(b) << 16);
}

// ---------------------------------------------------------------------------
// All 4 weight transposes in one launch. in [K][N=512] f32 -> out [N][K] bf16.
// ---------------------------------------------------------------------------
__global__ __launch_bounds__(256) void wtrans_all_kernel(
    const float* __restrict__ wq, const float* __restrict__ wk,
    const float* __restrict__ wv, const float* __restrict__ wo,
    unsigned short* __restrict__ wqT, unsigned short* __restrict__ wkT,
    unsigned short* __restrict__ wvT, unsigned short* __restrict__ woT) {
  __shared__ float tile[32][33];
  int bid = blockIdx.x;
  const float* in;
  unsigned short* out;
  int K, r;
  if (bid < 256)       { in = wq; out = wqT; K = 512; r = bid; }
  else if (bid < 640)  { in = wk; out = wkT; K = 768; r = bid - 256; }
  else if (bid < 1024) { in = wv; out = wvT; K = 768; r = bid - 640; }
  else                 { in = wo; out = woT; K = 512; r = bid - 1024; }
  int n0 = (r & 15) * 32, k0 = (r >> 4) * 32;
  int tx = threadIdx.x, ty = threadIdx.y;
#pragma unroll
  for (int j = 0; j < 4; ++j)
    tile[ty * 4 + j][tx] = in[(size_t)(k0 + ty * 4 + j) * 512 + n0 + tx];
  __syncthreads();
#pragma unroll
  for (int j = 0; j < 4; ++j)
    out[(size_t)(n0 + ty * 4 + j) * K + k0 + tx] = f2bf(tile[tx][ty * 4 + j]);
}

// ---------------------------------------------------------------------------
// K/V projection (unchanged, proven)
// ---------------------------------------------------------------------------
__global__ __launch_bounds__(256) void kv_proj_kernel(const float* __restrict__ ctx,
                                                      const unsigned short* __restrict__ wkT,
                                                      const unsigned short* __restrict__ wvT,
                                                      const float* __restrict__ bk,
                                                      const float* __restrict__ bv,
                                                      unsigned short* __restrict__ Kp,
                                                      unsigned short* __restrict__ Vt) {
  __shared__ __align__(16) unsigned short As[64][40];
  __shared__ __align__(16) unsigned short Bs[64][40];
  int bid = blockIdx.x;
  int sel = bid / 80;
  int rem = bid % 80;
  int mt = rem / 8, nt = rem % 8;
  const unsigned short* wT = sel ? wvT : wkT;
  const float* bias = sel ? bv : bk;
  int tid = threadIdx.x;
  int l = tid & 63, w = tid >> 6;
  int lr = l & 15, lg = l >> 4;

  f32x4 acc[4] = {};
  for (int k0 = 0; k0 < 768; k0 += 32) {
#pragma unroll
    for (int it = 0; it < 2; ++it) {
      int idx4 = it * 256 + tid;
      int r = idx4 >> 3, q4 = idx4 & 7;
      int m = mt * 64 + r;
      float4 v = {0.f, 0.f, 0.f, 0.f};
      if (m < 616) v = *(const float4*)(ctx + (size_t)m * 768 + k0 + q4 * 4);
      ushort4 o;
      o.x = f2bf(v.x); o.y = f2bf(v.y); o.z = f2bf(v.z); o.w = f2bf(v.w);
      *(ushort4*)&As[r][q4 * 4] = o;
    }
    {
      int c = tid >> 2, q8 = tid & 3;
      *(uint4*)&Bs[c][q8 * 8] =
          *(const uint4*)(wT + (size_t)(nt * 64 + c) * 768 + k0 + q8 * 8);
    }
    __syncthreads();
    bf16x8 a = *(const bf16x8*)&As[w * 16 + lr][lg * 8];
#pragma unroll
    for (int n = 0; n < 4; ++n) {
      bf16x8 bb = *(const bf16x8*)&Bs[n * 16 + lr][lg * 8];
      acc[n] = __builtin_amdgcn_mfma_f32_16x16x32_bf16(a, bb, acc[n], 0, 0, 0);
    }
    __syncthreads();
  }
#pragma unroll
  for (int n = 0; n < 4; ++n) {
#pragma unroll
    for (int reg = 0; reg < 4; ++reg) {
      int m = mt * 64 + w * 16 + lg * 4 + reg;
      if (m < 616) {
        int bI = m / 77, s = m % 77;
        int col = nt * 64 + n * 16 + lr;
        int h = col >> 6, d = col & 63;
        float v = acc[n][reg] + bias[col];
        if (sel == 0)
          Kp[(((size_t)(bI * 8 + h)) * 80 + s) * 64 + d] = f2bf(v);
        else
          Vt[(((size_t)(bI * 8 + h)) * 64 + d) * 96 + s] = f2bf(v);
      }
    }
  }
}

// ---------------------------------------------------------------------------
// FUSED Q-proj + attention, v3 (2-phase dbuf + XCD swizzle).
// ---------------------------------------------------------------------------
__global__ __launch_bounds__(256, 4) void qproj_attn_kernel(
    const float* __restrict__ A32, const unsigned short* __restrict__ BT,
    const float* __restrict__ bias, const unsigned short* __restrict__ Kp,
    const unsigned short* __restrict__ Vt, unsigned short* __restrict__ Oq) {
  __shared__ __align__(16) char smem[36864];
  unsigned short* As = (unsigned short*)smem;            // [2][128*32] 16KB
  unsigned short* Bs = (unsigned short*)(smem + 16384);  // [2][128*32] 16KB
  unsigned short* Qw = (unsigned short*)smem;            // [4][64][72] overlay

  // XCD-bijective swizzle: 1024 blocks, 8 XCDs, 128/XCD; the 4 N-tile
  // siblings of an A panel are consecutive -> same XCD L2.
  int bid = ((blockIdx.x & 7) << 7) | (blockIdx.x >> 3);
  size_t mbase = (size_t)(bid >> 2) * 128;
  int nbase = (bid & 3) * 128;
  int tid = threadIdx.x;
  int l = tid & 63, w = tid >> 6;
  int lr = l & 15, lg = l >> 4;
  int wr = (w >> 1) * 64, wc = (w & 1) * 64;

  const float* pA0 = A32 + (mbase + (tid >> 2)) * 512 + (tid & 3) * 8;
  const float* pA1 = pA0 + (size_t)64 * 512;
  const unsigned short* gB = BT + (size_t)(nbase + w * 32 + (l >> 2)) * 512 + (l & 3) * 8;

  // ---- prologue: stage k0=0 into buf0 ----
  {
    float4 x0 = *(const float4*)(pA0);
    float4 x1 = *(const float4*)(pA0 + 4);
    float4 x2 = *(const float4*)(pA1);
    float4 x3 = *(const float4*)(pA1 + 4);
    GLDS16(gB, Bs + w * 1024);
    GLDS16(gB + 16 * 512, Bs + w * 1024 + 512);
    uint4 u0, u1;
    u0.x = pack2bf(x0.x, x0.y); u0.y = pack2bf(x0.z, x0.w);
    u0.z = pack2bf(x1.x, x1.y); u0.w = pack2bf(x1.z, x1.w);
    u1.x = pack2bf(x2.x, x2.y); u1.y = pack2bf(x2.z, x2.w);
    u1.z = pack2bf(x3.x, x3.y); u1.w = pack2bf(x3.z, x3.w);
    *(uint4*)&As[tid * 8] = u0;
    *(uint4*)&As[tid * 8 + 2048] = u1;
  }
  __syncthreads();

  f32x4 acc[4][4] = {};
#pragma unroll
  for (int k0 = 0; k0 < 512; k0 += 32) {
    const int cur = (k0 >> 5) & 1;
    const int nxt = cur ^ 1;
    unsigned short* curA = As + cur * 4096;
    unsigned short* curB = Bs + cur * 4096;
    const bool more = (k0 < 480);
    float4 x0, x1, x2, x3;
    if (more) {
      // issue next-phase loads FIRST: A float4s (regs) then B GLDS.
      x0 = *(const float4*)(pA0 + k0 + 32);
      x1 = *(const float4*)(pA0 + k0 + 36);
      x2 = *(const float4*)(pA1 + k0 + 32);
      x3 = *(const float4*)(pA1 + k0 + 36);
      GLDS16(gB + k0 + 32, Bs + nxt * 4096 + w * 1024);
      GLDS16(gB + k0 + 32 + 16 * 512, Bs + nxt * 4096 + w * 1024 + 512);
    }
    // compute current buffer
    bf16x8 af[4], bv8[4];
#pragma unroll
    for (int m = 0; m < 4; ++m)
      af[m] = *(const bf16x8*)&curA[(wr + m * 16 + lr) * 32 + lg * 8];
#pragma unroll
    for (int n = 0; n < 4; ++n)
      bv8[n] = *(const bf16x8*)&curB[(wc + n * 16 + lr) * 32 + lg * 8];
#pragma unroll
    for (int m = 0; m < 4; ++m)
#pragma unroll
      for (int n = 0; n < 4; ++n)
        acc[m][n] = __builtin_amdgcn_mfma_f32_16x16x32_bf16(af[m], bv8[n], acc[m][n], 0, 0, 0);
    if (more) {
      // cvt+write next A (waits only on the A loads; B GLDS still in flight)
      uint4 u0, u1;
      u0.x = pack2bf(x0.x, x0.y); u0.y = pack2bf(x0.z, x0.w);
      u0.z = pack2bf(x1.x, x1.y); u0.w = pack2bf(x1.z, x1.w);
      u1.x = pack2bf(x2.x, x2.y); u1.y = pack2bf(x2.z, x2.w);
      u1.z = pack2bf(x3.x, x3.y); u1.w = pack2bf(x3.z, x3.w);
      *(uint4*)&As[nxt * 4096 + tid * 8] = u0;
      *(uint4*)&As[nxt * 4096 + tid * 8 + 2048] = u1;
    }
    __syncthreads();
  }

  // ---- epilogue: Q quadrant -> wave-private LDS (transpose), +bias ----
  unsigned short* Qme = Qw + w * (64 * 72);
  float bb[4];
#pragma unroll
  for (int n = 0; n < 4; ++n) bb[n] = bias[nbase + wc + n * 16 + lr];
#pragma unroll
  for (int m = 0; m < 4; ++m)
#pragma unroll
    for (int n = 0; n < 4; ++n)
#pragma unroll
      for (int reg = 0; reg < 4; ++reg)
        Qme[(m * 16 + lg * 4 + reg) * 72 + n * 16 + lr] = f2bf(acc[m][n][reg] + bb[n]);

  // preload ALL Q frags to regs (wave-local LDS RAW: compiler orders)
  bf16x8 qf[4][2];
#pragma unroll
  for (int rg = 0; rg < 4; ++rg) {
    qf[rg][0] = *(const bf16x8*)&Qme[(rg * 16 + lr) * 72 + lg * 8];
    qf[rg][1] = *(const bf16x8*)&Qme[(rg * 16 + lr) * 72 + 32 + lg * 8];
  }
  __syncthreads();  // all waves done with Qw -> safe to overlay P

  // P overlaid at smem base: per-wave 16 rows x 104 cols bf16 (3328 B)
  unsigned short* Pme = (unsigned short*)smem + w * 1664;
  for (int z = l; z < 256; z += 64) Pme[(z >> 4) * 104 + 80 + (z & 15)] = 0;

  // ---- wave-local attention: 64 q-rows x head h ----
  int b = (int)(mbase >> 12);
  int h = (bid & 3) * 2 + (w & 1);
  const unsigned short* Kph = Kp + (size_t)(b * 8 + h) * (80 * 64);
  const unsigned short* Vth = Vt + (size_t)(b * 8 + h) * (64 * 96);

  const float C = 0.125f * 1.44269504088896f;  // 1/sqrt(64) * log2(e)

  auto QK = [&](int rg, f32x4* s) {
#pragma unroll
    for (int t = 0; t < 5; ++t) {
      const unsigned short* kr = Kph + (t * 16 + lr) * 64 + lg * 8;
      bf16x8 k0 = *(const bf16x8*)kr;
      bf16x8 k1 = *(const bf16x8*)(kr + 32);
      s[t] = __builtin_amdgcn_mfma_f32_16x16x32_bf16(qf[rg][0], k0, s[t], 0, 0, 0);
      s[t] = __builtin_amdgcn_mfma_f32_16x16x32_bf16(qf[rg][1], k1, s[t], 0, 0, 0);
    }
    if (lr >= 13) {  // cols 64+lr >= 77 are pad
      s[4][0] = -1e30f; s[4][1] = -1e30f; s[4][2] = -1e30f; s[4][3] = -1e30f;
    }
  };

  f32x4 sc[5] = {};
  QK(0, sc);
#pragma unroll
  for (int rg = 0; rg < 4; ++rg) {
    float mx[4], sm[4];
#pragma unroll
    for (int r = 0; r < 4; ++r)
      mx[r] = fmaxf(fmaxf(fmaxf(sc[0][r], sc[1][r]), fmaxf(sc[2][r], sc[3][r])), sc[4][r]);
#pragma unroll
    for (int d = 1; d < 16; d <<= 1)
#pragma unroll
      for (int r = 0; r < 4; ++r) mx[r] = fmaxf(mx[r], __shfl_xor(mx[r], d, 64));
    float p[5][4];
#pragma unroll
    for (int t = 0; t < 5; ++t)
#pragma unroll
      for (int r = 0; r < 4; ++r) p[t][r] = exp2f((sc[t][r] - mx[r]) * C);
#pragma unroll
    for (int r = 0; r < 4; ++r)
      sm[r] = p[0][r] + p[1][r] + p[2][r] + p[3][r] + p[4][r];
#pragma unroll
    for (int d = 1; d < 16; d <<= 1)
#pragma unroll
      for (int r = 0; r < 4; ++r) sm[r] += __shfl_xor(sm[r], d, 64);
#pragma unroll
    for (int r = 0; r < 4; ++r) sm[r] = 1.0f / sm[r];
#pragma unroll
    for (int t = 0; t < 5; ++t)
#pragma unroll
      for (int r = 0; r < 4; ++r)
        Pme[(lg * 4 + r) * 104 + t * 16 + lr] = f2bf(p[t][r] * sm[r]);

    f32x4 sn[5] = {};
    if (rg < 3) QK(rg + 1, sn);

    bf16x8 ap[3];
#pragma unroll
    for (int c = 0; c < 3; ++c) ap[c] = *(const bf16x8*)&Pme[lr * 104 + c * 32 + lg * 8];
#pragma unroll
    for (int ct = 0; ct < 4; ++ct) {
      f32x4 o = {};
#pragma unroll
      for (int c = 0; c < 3; ++c) {
        bf16x8 vv = *(const bf16x8*)(Vth + (size_t)(ct * 16 + lr) * 96 + c * 32 + lg * 8);
        o = __builtin_amdgcn_mfma_f32_16x16x32_bf16(ap[c], vv, o, 0, 0, 0);
      }
#pragma unroll
      for (int reg = 0; reg < 4; ++reg)
        Oq[(mbase + wr + rg * 16 + lg * 4 + reg) * 512 + nbase + wc + ct * 16 + lr] =
            f2bf(o[reg]);
    }
#pragma unroll
    for (int t = 0; t < 5; ++t) sc[t] = sn[t];
  }
}

// ---------------------------------------------------------------------------
// m97-style GEMM for O-proj (+XCD swizzle): A[32768][512]bf16 @ woT + bo -> f32
// ---------------------------------------------------------------------------
__global__ __launch_bounds__(256) void gemm512_glds_kernel(
    const unsigned short* __restrict__ A, const unsigned short* __restrict__ BT,
    const float* __restrict__ bias, float* __restrict__ Out) {
  __shared__ __align__(16) unsigned short As[128 * 32];
  __shared__ __align__(16) unsigned short Bs[128 * 32];
  int bid = ((blockIdx.x & 7) << 7) | (blockIdx.x >> 3);  // XCD swizzle
  size_t mbase = (size_t)(bid >> 2) * 128;
  int nbase = (bid & 3) * 128;
  int tid = threadIdx.x;
  int l = tid & 63, w = tid >> 6;
  int lr = l & 15, lg = l >> 4;
  int wr = (w >> 1) * 64, wc = (w & 1) * 64;

  const unsigned short* gA = A + (mbase + w * 32 + (l >> 2)) * 512 + (l & 3) * 8;
  const unsigned short* gB = BT + (size_t)(nbase + w * 32 + (l >> 2)) * 512 + (l & 3) * 8;
  unsigned short* lA = As + w * 1024;
  unsigned short* lB = Bs + w * 1024;

  f32x4 acc[4][4] = {};
  for (int k0 = 0; k0 < 512; k0 += 32) {
    GLDS16(gA + k0, lA);
    GLDS16(gA + k0 + 16 * 512, lA + 512);
    GLDS16(gB + k0, lB);
    GLDS16(gB + k0 + 16 * 512, lB + 512);
    asm volatile("s_waitcnt vmcnt(0)" ::: "memory");
    __syncthreads();
    bf16x8 af[4], bv8[4];
#pragma unroll
    for (int m = 0; m < 4; ++m)
      af[m] = *(const bf16x8*)&As[(wr + m * 16 + lr) * 32 + lg * 8];
#pragma unroll
    for (int n = 0; n < 4; ++n)
      bv8[n] = *(const bf16x8*)&Bs[(wc + n * 16 + lr) * 32 + lg * 8];
#pragma unroll
    for (int m = 0; m < 4; ++m)
#pragma unroll
      for (int n = 0; n < 4; ++n)
        acc[m][n] = __builtin_amdgcn_mfma_f32_16x16x32_bf16(af[m], bv8[n], acc[m][n], 0, 0, 0);
    __syncthreads();
  }
#pragma unroll
  for (int m = 0; m < 4; ++m) {
#pragma unroll
    for (int n = 0; n < 4; ++n) {
#pragma unroll
      for (int reg = 0; reg < 4; ++reg) {
        size_t row = mbase + wr + m * 16 + lg * 4 + reg;
        int col = nbase + wc + n * 16 + lr;
        Out[row * 512 + col] = acc[m][n][reg] + bias[col];
      }
    }
  }
}

// ---------------------------------------------------------------------------
// Workspace layout (bytes)
// ---------------------------------------------------------------------------
static const size_t OFF_Q   = 0;                         // 8*4096*512*2 = 33554432
static const size_t OFF_KP  = 33554432;                  // 8*8*80*64*2  = 655360
static const size_t OFF_VT  = OFF_KP + 655360;           // 8*8*64*96*2  = 786432
static const size_t OFF_WQT = OFF_VT + 786432;           // 512*512*2
static const size_t OFF_WKT = OFF_WQT + 524288;          // 512*768*2
static const size_t OFF_WVT = OFF_WKT + 786432;          // 512*768*2
static const size_t OFF_WOT = OFF_WVT + 786432;          // 512*512*2
static const size_t WS_NEEDED = OFF_WOT + 524288;        // 37617664

extern "C" void kernel_launch(void* const* d_in, const int* in_sizes, int n_in,
                              void* d_out, int out_size, void* d_ws, size_t ws_size,
                              hipStream_t stream) {
  (void)in_sizes; (void)n_in; (void)out_size;
  if (ws_size < WS_NEEDED) return;

  const float* latent  = (const float*)d_in[0];
  const float* context = (const float*)d_in[1];
  const float* wq = (const float*)d_in[2];
  const float* bq = (const float*)d_in[3];
  const float* wk = (const float*)d_in[4];
  const float* bk = (const float*)d_in[5];
  const float* wv = (const float*)d_in[6];
  const float* bv = (const float*)d_in[7];
  const float* wo = (const float*)d_in[8];
  const float* bo = (const float*)d_in[9];
  float* out = (float*)d_out;

  char* ws = (char*)d_ws;
  unsigned short* wsQ = (unsigned short*)(ws + OFF_Q);   // attn output (bf16)
  unsigned short* Kp  = (unsigned short*)(ws + OFF_KP);
  unsigned short* Vt  = (unsigned short*)(ws + OFF_VT);
  unsigned short* wqT = (unsigned short*)(ws + OFF_WQT);
  unsigned short* wkT = (unsigned short*)(ws + OFF_WKT);
  unsigned short* wvT = (unsigned short*)(ws + OFF_WVT);
  unsigned short* woT = (unsigned short*)(ws + OFF_WOT);

  wtrans_all_kernel<<<1280, dim3(32, 8), 0, stream>>>(wq, wk, wv, wo,
                                                      wqT, wkT, wvT, woT);
  hipMemsetAsync(ws + OFF_KP, 0, 655360 + 786432, stream);
  kv_proj_kernel<<<160, 256, 0, stream>>>(context, wkT, wvT, bk, bv, Kp, Vt);
  qproj_attn_kernel<<<1024, 256, 0, stream>>>(latent, wqT, bq, Kp, Vt, wsQ);
  gemm512_glds_kernel<<<1024, 256, 0, stream>>>(wsQ, woT, bo, out);
}